// Round 6
// baseline (109.987 us; speedup 1.0000x reference)
//
#include <hip/hip_runtime.h>
#include <hip/hip_bf16.h>
#include <stdint.h>

typedef short short8 __attribute__((ext_vector_type(8)));
typedef float f32x4 __attribute__((ext_vector_type(4)));
typedef unsigned short ushort4v __attribute__((ext_vector_type(4)));

#define MDIM 8192
#define KDIM 1024
#define NDIM 1024
#define NKT  16

// ---------- helpers ----------

__device__ __forceinline__ unsigned short f2bf(float f) {
  union { float f; unsigned int u; } v; v.f = f;
  unsigned int u = v.u;
  u += 0x7fffu + ((u >> 16) & 1u);
  return (unsigned short)(u >> 16);
}

__device__ __forceinline__ void load_lds16(const void* gsrc, void* ldst) {
  __builtin_amdgcn_global_load_lds(
      (__attribute__((address_space(1))) void*)gsrc,
      (__attribute__((address_space(3))) void*)ldst,
      16, 0, 0);
}

__device__ __forceinline__ float fast_sigmoid(float x) {
  return 1.0f / (1.0f + __expf(-x));
}

__device__ __forceinline__ float fast_tanh(float x) {
  x = fminf(30.0f, fmaxf(-30.0f, x));
  float e = __expf(-2.0f * x);
  return (1.0f - e) / (1.0f + e);
}

// ---------- conversion kernels ----------

// hprev f32 [M][K] -> A_t[kt][M][64] bf16 (K-tile panels, 128 B rows)
__global__ void convert_h_tiled(const float* __restrict__ in,
                                unsigned short* __restrict__ out, int nchunk) {
  int idx = blockIdx.x * blockDim.x + threadIdx.x;
  int stride = gridDim.x * blockDim.x;
  for (int i = idx; i < nchunk; i += stride) {
    int r = i >> 7;
    int kc8 = i & 127;
    const float4* src = reinterpret_cast<const float4*>(in + (size_t)r * KDIM + kc8 * 8);
    float4 v0 = src[0], v1 = src[1];
    short8 o;
    o[0] = (short)f2bf(v0.x); o[1] = (short)f2bf(v0.y);
    o[2] = (short)f2bf(v0.z); o[3] = (short)f2bf(v0.w);
    o[4] = (short)f2bf(v1.x); o[5] = (short)f2bf(v1.y);
    o[6] = (short)f2bf(v1.z); o[7] = (short)f2bf(v1.w);
    int kt = kc8 >> 3;
    int c8 = kc8 & 7;
    reinterpret_cast<short8*>(out)[((size_t)kt * MDIM + r) * 8 + c8] = o;
  }
}

// w[k][n] f32 -> B_lin MFMA-fragment-linear bf16:
// 16B block index = (((kt*2+kk)*4+g)*64 + n/16)*64 + lane,
// element e of lane l = w[kt*64+kk*32+(l>>4)*8+e][ (n/16)*16 + (l&15) ]
__global__ void convert_w_fraglin(const float* __restrict__ w0,
                                  const float* __restrict__ w1,
                                  const float* __restrict__ w2,
                                  const float* __restrict__ w3,
                                  unsigned short* __restrict__ out) {
  __shared__ float tile[64][65];
  int g = blockIdx.z;
  const float* w = (g == 0) ? w0 : (g == 1) ? w1 : (g == 2) ? w2 : w3;
  int kt = blockIdx.y;
  int k0 = kt * 64;
  int n0 = blockIdx.x * 64;
  int tx = threadIdx.x;   // 0..63 (lane)
  int ty = threadIdx.y;   // 0..3
#pragma unroll
  for (int j = 0; j < 16; ++j) {
    int kk = ty * 16 + j;
    tile[kk][tx] = w[(size_t)(k0 + kk) * NDIM + n0 + tx];
  }
  __syncthreads();
#pragma unroll
  for (int wit = 0; wit < 2; ++wit) {
    int idx = ty * 2 + wit;         // 0..7
    int kk = idx >> 2;              // 0..1
    int sl = idx & 3;               // local 16-col slice
    short8 o;
#pragma unroll
    for (int e = 0; e < 8; ++e)
      o[e] = (short)f2bf(tile[kk * 32 + (tx >> 4) * 8 + e][sl * 16 + (tx & 15)]);
    reinterpret_cast<short8*>(out)[
        ((((size_t)kt * 2 + kk) * 4 + g) * 64 + (n0 >> 4) + sl) * 64 + tx] = o;
  }
}

// ---------- fused 4-gate GEMM: A via LDS dbuf, B direct-to-register ----------
//
// 512 thr = 8 waves (2M x 4N). Tile 256 rows x (4 gates x 64 cols), BK=64.
// A: LDS 2 x 32 KB, XOR chunk swizzle (R4 scheme, measured 0 conflicts),
//    staged with global_load_lds w16: ONE glds instr = 512 thr x 16 B = 8 KB
//    => exactly 4 instrs per 32 KB tile (R5 bug: 8 instrs = 64 KB overrun
//    smashing the live buffer).
// B: fragment-linear global loads straight to registers (1 KB coalesced per
//    frag, L2-resident, 8x register reuse per frag) -> no LDS, no barriers.
// Per tile VMEM ledger (12 ops): {B-kk1 x4, A-glds x4, B-next-kk0 x4};
// tile end: vmcnt(4) retires glds (+B-kk1), leaves B-next in flight;
// ONE s_barrier per K-tile (16 total).

#define BUFA0 0
#define BUFA1 32768

#define SB() __builtin_amdgcn_sched_barrier(0)

#define LDA4(CUR, mb_, ss) do { \
    Af0 = *(const short8*)(ldsb + (CUR) + ar + ((mb_) + 0) * 2048 + (ss)); \
    Af1 = *(const short8*)(ldsb + (CUR) + ar + ((mb_) + 1) * 2048 + (ss)); \
    Af2 = *(const short8*)(ldsb + (CUR) + ar + ((mb_) + 2) * 2048 + (ss)); \
    Af3 = *(const short8*)(ldsb + (CUR) + ar + ((mb_) + 3) * 2048 + (ss)); } while (0)

#define MROW(BP, m_, AF) do { \
    acc[0][m_] = __builtin_amdgcn_mfma_f32_16x16x32_bf16(AF, BP##0, acc[0][m_], 0, 0, 0); \
    acc[1][m_] = __builtin_amdgcn_mfma_f32_16x16x32_bf16(AF, BP##1, acc[1][m_], 0, 0, 0); \
    acc[2][m_] = __builtin_amdgcn_mfma_f32_16x16x32_bf16(AF, BP##2, acc[2][m_], 0, 0, 0); \
    acc[3][m_] = __builtin_amdgcn_mfma_f32_16x16x32_bf16(AF, BP##3, acc[3][m_], 0, 0, 0); } while (0)

#define MFMA16(BP, mb_) do { \
    __builtin_amdgcn_s_setprio(1); \
    MROW(BP, (mb_) + 0, Af0); MROW(BP, (mb_) + 1, Af1); \
    MROW(BP, (mb_) + 2, Af2); MROW(BP, (mb_) + 3, Af3); \
    __builtin_amdgcn_s_setprio(0); } while (0)

// BC = current tile's kk0 B-frags (prefix), BN = next tile's kk0 (prefix)
#define TILE(t_, CUR, NXT, BC, BN) do { \
    const uint32_t tn_ = ((t_) + 1) & (NKT - 1); \
    short8 q0, q1, q2, q3; \
    SB(); \
    q0 = *(const short8*)(bb + ((((uint32_t)(t_) * 2 + 1) * 4 + 0) << 16) + bv); \
    q1 = *(const short8*)(bb + ((((uint32_t)(t_) * 2 + 1) * 4 + 1) << 16) + bv); \
    q2 = *(const short8*)(bb + ((((uint32_t)(t_) * 2 + 1) * 4 + 2) << 16) + bv); \
    q3 = *(const short8*)(bb + ((((uint32_t)(t_) * 2 + 1) * 4 + 3) << 16) + bv); \
    SB(); \
    _Pragma("unroll") \
    for (int j = 0; j < 4; ++j) \
      load_lds16(ab + ((size_t)tn_ << 20) + srcA + j * 8192, \
                 ldsb + (NXT) + j * 8192 + tid * 16); \
    SB(); \
    BN##0 = *(const short8*)(bb + (((tn_ * 2 + 0) * 4 + 0) << 16) + bv); \
    BN##1 = *(const short8*)(bb + (((tn_ * 2 + 0) * 4 + 1) << 16) + bv); \
    BN##2 = *(const short8*)(bb + (((tn_ * 2 + 0) * 4 + 2) << 16) + bv); \
    BN##3 = *(const short8*)(bb + (((tn_ * 2 + 0) * 4 + 3) << 16) + bv); \
    SB(); \
    LDA4(CUR, 0, s0v); MFMA16(BC, 0); \
    LDA4(CUR, 4, s0v); MFMA16(BC, 4); \
    LDA4(CUR, 0, s1v); MFMA16(q, 0); \
    LDA4(CUR, 4, s1v); MFMA16(q, 4); \
    asm volatile("s_waitcnt vmcnt(4)" ::: "memory"); \
    __builtin_amdgcn_s_barrier(); } while (0)

__global__ __launch_bounds__(512, 2) void lstm_fused_gemm(
    const unsigned short* __restrict__ At,    // [16][8192][64] bf16
    const unsigned short* __restrict__ Blin,  // frag-linear, 8 MB
    const float* __restrict__ cprev,
    const float* __restrict__ b_i, const float* __restrict__ b_f,
    const float* __restrict__ b_g, const float* __restrict__ b_o,
    float* __restrict__ out)
{
  __shared__ unsigned char ldsb[65536];
  const int tid  = threadIdx.x;
  const int lane = tid & 63;
  const int wave = tid >> 6;
  const int wr = wave >> 2;   // 0..1
  const int wc = wave & 3;    // 0..3
  const int r15 = lane & 15;
  const int hh  = lane >> 4;

  // XCD swizzle: per XCD 64 blocks = 32 mb x 2 nb (keeps B L2-resident).
  int bid = blockIdx.x;
  int loc = bid >> 3;
  int nb = (bid & 7) * 2 + (loc >> 5);   // 0..15
  int mb = loc & 31;                     // 0..31
  int brow = mb * 256;
  int bcol = nb * 64;

  const char* ab = (const char*)At;
  const char* bb = (const char*)Blin;

  // A staging source (pre-swizzled chunk within 128 B line)
  const int arow = tid >> 3;
  const int cx = (((tid & 7) ^ (arow & 7)) << 4);
  const uint32_t srcA = (uint32_t)(brow + arow) * 128 + cx;

  // A fragment read offsets
  const uint32_t ar = (uint32_t)(wr * 128 + r15) * 128;
  const int s0v = ((hh ^ (r15 & 7)) << 4);
  const int s1v = s0v ^ 64;

  // B fragment voffset
  const uint32_t bv = ((uint32_t)(nb * 4 + wc) << 10) + lane * 16;

  f32x4 acc[4][8];
#pragma unroll
  for (int g = 0; g < 4; ++g)
#pragma unroll
    for (int m = 0; m < 8; ++m)
      acc[g][m] = (f32x4){0.f, 0.f, 0.f, 0.f};

  short8 Af0, Af1, Af2, Af3;
  short8 bA0, bA1, bA2, bA3, bB0, bB1, bB2, bB3;

  // prologue: stage A tile0 into BUFA0 (4 x 8 KB = 32 KB); load B(t0,kk0)
#pragma unroll
  for (int j = 0; j < 4; ++j)
    load_lds16(ab + srcA + j * 8192, ldsb + BUFA0 + j * 8192 + tid * 16);
  bA0 = *(const short8*)(bb + (0u << 16) + bv);
  bA1 = *(const short8*)(bb + (1u << 16) + bv);
  bA2 = *(const short8*)(bb + (2u << 16) + bv);
  bA3 = *(const short8*)(bb + (3u << 16) + bv);
  asm volatile("s_waitcnt vmcnt(0)" ::: "memory");
  __builtin_amdgcn_s_barrier();

  for (int it = 0; it < NKT / 2; ++it) {
    TILE(2 * it,     BUFA0, BUFA1, bA, bB);
    TILE(2 * it + 1, BUFA1, BUFA0, bB, bA);
  }

  // ---- fused LSTM epilogue ----
  // C/D layout: col = lane&15, row = (lane>>4)*4 + j.
  const size_t outC = (size_t)MDIM * NDIM;
  const int cc = bcol + wc * 16 + r15;
  const float bi = b_i[cc], bff = b_f[cc], bg = b_g[cc], bo = b_o[cc];
#pragma unroll
  for (int m = 0; m < 8; ++m) {
#pragma unroll
    for (int j = 0; j < 4; ++j) {
      int rr = brow + wr * 128 + m * 16 + hh * 4 + j;
      size_t base = (size_t)rr * NDIM + cc;
      float pi = acc[0][m][j] + bi;
      float pf = acc[1][m][j] + bff;
      float pg = acc[2][m][j] + bg;
      float po = acc[3][m][j] + bo;
      float iv = fast_sigmoid(pi);
      float fv = fast_sigmoid(pf);
      float gv = fast_tanh(pg);
      float ov = fast_sigmoid(po);
      float cp = fv * cprev[base] + iv * gv;
      float hp = ov * fast_tanh(cp);
      out[base] = hp;
      out[outC + base] = cp;
    }
  }
}

// ---------- launch ----------

extern "C" void kernel_launch(void* const* d_in, const int* in_sizes, int n_in,
                              void* d_out, int out_size, void* d_ws, size_t ws_size,
                              hipStream_t stream) {
  const float* hprev = (const float*)d_in[0];
  const float* cprev = (const float*)d_in[1];
  const float* w_hi  = (const float*)d_in[2];
  const float* b_hi  = (const float*)d_in[3];
  const float* w_hf  = (const float*)d_in[4];
  const float* b_hf  = (const float*)d_in[5];
  const float* w_hg  = (const float*)d_in[6];
  const float* b_hg  = (const float*)d_in[7];
  const float* w_ho  = (const float*)d_in[8];
  const float* b_ho  = (const float*)d_in[9];
  float* out = (float*)d_out;

  // ws: [0,16MB) A_t; [16MB,24MB) B_lin
  unsigned short* At   = (unsigned short*)d_ws;
  unsigned short* Blin = (unsigned short*)((char*)d_ws + (size_t)NKT * MDIM * 64 * 2);

  convert_h_tiled<<<2048, 256, 0, stream>>>(hprev, At, MDIM * KDIM / 8);
  convert_w_fraglin<<<dim3(16, 16, 4), dim3(64, 4, 1), 0, stream>>>(
      w_hi, w_hf, w_hg, w_ho, Blin);
  lstm_fused_gemm<<<512, 512, 0, stream>>>(At, Blin, cprev,
                                           b_hi, b_hf, b_hg, b_ho, out);
}

// Round 7
// 105.624 us; speedup vs baseline: 1.0413x; 1.0413x over previous
//
#include <hip/hip_runtime.h>
#include <hip/hip_bf16.h>
#include <stdint.h>

typedef short short8 __attribute__((ext_vector_type(8)));
typedef float f32x4 __attribute__((ext_vector_type(4)));

#define MDIM 8192
#define KDIM 1024
#define NDIM 1024
#define NKT  16

// ---------- helpers ----------

__device__ __forceinline__ unsigned short f2bf(float f) {
  union { float f; unsigned int u; } v; v.f = f;
  unsigned int u = v.u;
  u += 0x7fffu + ((u >> 16) & 1u);
  return (unsigned short)(u >> 16);
}

__device__ __forceinline__ void load_lds16(const void* gsrc, void* ldst) {
  __builtin_amdgcn_global_load_lds(
      (__attribute__((address_space(1))) void*)gsrc,
      (__attribute__((address_space(3))) void*)ldst,
      16, 0, 0);
}

__device__ __forceinline__ float fast_sigmoid(float x) {
  return 1.0f / (1.0f + __expf(-x));
}

__device__ __forceinline__ float fast_tanh(float x) {
  x = fminf(30.0f, fmaxf(-30.0f, x));
  float e = __expf(-2.0f * x);
  return (1.0f - e) / (1.0f + e);
}

// ---------- conversion kernels (tiled bf16 workspace) ----------

// hprev f32 [M][K] -> A_t[kt][M][64] bf16 (K-tile panels, 128 B rows)
__global__ void convert_h_tiled(const float* __restrict__ in,
                                unsigned short* __restrict__ out, int nchunk) {
  int idx = blockIdx.x * blockDim.x + threadIdx.x;
  int stride = gridDim.x * blockDim.x;
  for (int i = idx; i < nchunk; i += stride) {
    int r = i >> 7;
    int kc8 = i & 127;
    const float4* src = reinterpret_cast<const float4*>(in + (size_t)r * KDIM + kc8 * 8);
    float4 v0 = src[0], v1 = src[1];
    short8 o;
    o[0] = (short)f2bf(v0.x); o[1] = (short)f2bf(v0.y);
    o[2] = (short)f2bf(v0.z); o[3] = (short)f2bf(v0.w);
    o[4] = (short)f2bf(v1.x); o[5] = (short)f2bf(v1.y);
    o[6] = (short)f2bf(v1.z); o[7] = (short)f2bf(v1.w);
    int kt = kc8 >> 3;
    int c8 = kc8 & 7;
    reinterpret_cast<short8*>(out)[((size_t)kt * MDIM + r) * 8 + c8] = o;
  }
}

// w[k][n] f32 -> B_t[kt][g][N][64] bf16 (transpose + tile, 128 B rows)
__global__ void convert_w_tiled(const float* __restrict__ w0,
                                const float* __restrict__ w1,
                                const float* __restrict__ w2,
                                const float* __restrict__ w3,
                                unsigned short* __restrict__ out) {
  __shared__ float tile[64][65];
  int g = blockIdx.z;
  const float* w = (g == 0) ? w0 : (g == 1) ? w1 : (g == 2) ? w2 : w3;
  int kt = blockIdx.y;
  int k0 = kt * 64;
  int n0 = blockIdx.x * 64;
  int tx = threadIdx.x;
  int ty = threadIdx.y;
#pragma unroll
  for (int j = 0; j < 16; ++j) {
    int kk = ty * 16 + j;
    tile[kk][tx] = w[(size_t)(k0 + kk) * NDIM + n0 + tx];
  }
  __syncthreads();
#pragma unroll
  for (int j = 0; j < 16; ++j) {
    int nn = ty * 16 + j;
    out[(((size_t)kt * 4 + g) * NDIM + n0 + nn) * 64 + tx] = f2bf(tile[tx][nn]);
  }
}

// ---------- fused 4-gate GEMM: faithful 8-phase (m201) schedule ----------
//
// 512 thr = 8 waves (2M x 4N). Tile 256 rows x (4 gates x 64 cols), BK=64.
// LDS 128 KB: buf X0/X1, each { A[256][128B] | B[256][128B] }, XOR chunk
// swizzle slot=c^(r&7) (R4 scheme, measured 0 conflicts), swizzle folded
// into the pre-swizzled GLOBAL source (LDS dest linear for glds).
// Per K-tile block (4 phases): ph0: 16 ds_read (all-B + A-qm0) + stage
// (t+1).A1 -> other buf; ph1: stage (t+2).B0; ph2: 8 ds_read (A-qm1) +
// stage (t+2).B1; ph3: stage (t+2).A0 + vmcnt(6).
// Flight ledger: 3 half-tiles (6 loads) outstanding at each block end;
// tile t fully landed before its block (vmcnt(6) drains (t).A1).

#define X0 0
#define X1 65536

#define BAR() __builtin_amdgcn_s_barrier()
#define LGKM0() do { \
    asm volatile("s_waitcnt lgkmcnt(0)" ::: "memory"); \
    __builtin_amdgcn_sched_barrier(0); } while (0)
#define VM6() asm volatile("s_waitcnt vmcnt(6)" ::: "memory")

#define STG_A(BUF, ktv, h) do { \
    const uint32_t _oA = ((uint32_t)(ktv) << 20) + srcA + (h) * 16384; \
    load_lds16(ab + _oA,        ldsb + (BUF) + (h) * 16384 + tid * 16); \
    load_lds16(ab + _oA + 8192, ldsb + (BUF) + (h) * 16384 + 8192 + tid * 16); } while (0)
#define STG_B(BUF, ktv, h) do { \
    const uint32_t _oB = ((uint32_t)(ktv) << 19) + srcB0 + (h) * 262144; \
    load_lds16(bb + _oB,          ldsb + (BUF) + 32768 + (h) * 16384 + tid * 16); \
    load_lds16(bb + _oB + 131072, ldsb + (BUF) + 32768 + (h) * 16384 + 8192 + tid * 16); } while (0)

#define LDB_ALL(CB) do { \
    _Pragma("unroll") for (int g = 0; g < 4; ++g) { \
      Br[g * 2 + 0] = *(const short8*)(ldsb + (CB) + b_base + g * 8192 + s0v); \
      Br[g * 2 + 1] = *(const short8*)(ldsb + (CB) + b_base + g * 8192 + s1v); } } while (0)
#define LDA_Q(CB, qm) do { \
    _Pragma("unroll") for (int f = 0; f < 4; ++f) { \
      Ar[f * 2 + 0] = *(const short8*)(ldsb + (CB) + a_base + ((qm) * 64 + f * 16) * 128 + s0v); \
      Ar[f * 2 + 1] = *(const short8*)(ldsb + (CB) + a_base + ((qm) * 64 + f * 16) * 128 + s1v); } } while (0)

#define MFMAQ(qm, qn) do { \
    __builtin_amdgcn_s_setprio(1); \
    _Pragma("unroll") for (int kk = 0; kk < 2; ++kk) \
    _Pragma("unroll") for (int f = 0; f < 4; ++f) \
    _Pragma("unroll") for (int gg = 0; gg < 2; ++gg) \
      acc[(qn) * 2 + gg][(qm) * 4 + f] = __builtin_amdgcn_mfma_f32_16x16x32_bf16( \
          Ar[f * 2 + kk], Br[((qn) * 2 + gg) * 2 + kk], \
          acc[(qn) * 2 + gg][(qm) * 4 + f], 0, 0, 0); \
    __builtin_amdgcn_s_setprio(0); } while (0)

// One K-tile block: compute tile from CB; stage (tA1).A1->OB, (tN2).*->CB.
#define BLOCK4(CB, OB, tA1, tN2) do { \
    /* ph0 */ \
    LDB_ALL(CB); LDA_Q(CB, 0); \
    STG_A(OB, tA1, 1); \
    BAR(); LGKM0(); MFMAQ(0, 0); BAR(); \
    /* ph1 */ \
    STG_B(CB, tN2, 0); \
    BAR(); MFMAQ(0, 1); BAR(); \
    /* ph2 */ \
    LDA_Q(CB, 1); \
    STG_B(CB, tN2, 1); \
    BAR(); LGKM0(); MFMAQ(1, 0); BAR(); \
    /* ph3 */ \
    STG_A(CB, tN2, 0); \
    BAR(); MFMAQ(1, 1); VM6(); BAR(); } while (0)

__global__ __launch_bounds__(512, 2) void lstm_fused_gemm(
    const unsigned short* __restrict__ At,    // [16][8192][64] bf16
    const unsigned short* __restrict__ Bt,    // [16][4][1024][64] bf16
    const float* __restrict__ cprev,
    const float* __restrict__ b_i, const float* __restrict__ b_f,
    const float* __restrict__ b_g, const float* __restrict__ b_o,
    float* __restrict__ out)
{
  extern __shared__ unsigned char ldsb[];
  const int tid  = threadIdx.x;
  const int lane = tid & 63;
  const int wave = tid >> 6;
  const int wr = wave >> 2;   // 0..1 : rows wr*128..+128
  const int wc = wave & 3;    // 0..3 : cols wc*16..+16 per gate
  const int r15 = lane & 15;
  const int hh  = lane >> 4;

  // XCD swizzle: per XCD 2 nb x 32 mb (B panels L2-resident).
  int bid = blockIdx.x;
  int loc = bid >> 3;
  int nb = (bid & 7) * 2 + (loc >> 5);   // 0..15
  int mb = loc & 31;                     // 0..31
  int brow = mb * 256;
  int bcol = nb * 64;

  const char* ab = (const char*)At;
  const char* bb = (const char*)Bt;

  // staging source (pre-swizzled chunk within each 128 B line)
  const int srow = tid >> 3;
  const int cx = (((tid & 7) ^ (srow & 7)) << 4);
  const uint32_t srcA  = (uint32_t)(brow + srow) * 128 + cx;
  const uint32_t srcB0 = (uint32_t)(bcol + srow) * 128 + cx;

  // fragment read bases
  const uint32_t a_base = (uint32_t)(wr * 128 + r15) * 128;
  const uint32_t b_base = 32768u + (uint32_t)(wc * 16 + r15) * 128;
  const int s0v = ((hh ^ (r15 & 7)) << 4);
  const int s1v = s0v ^ 64;

  f32x4 acc[4][8];
#pragma unroll
  for (int g = 0; g < 4; ++g)
#pragma unroll
    for (int m = 0; m < 8; ++m)
      acc[g][m] = (f32x4){0.f, 0.f, 0.f, 0.f};

  short8 Ar[8], Br[8];

  // prologue: T0 complete -> X0 (8 loads), T1.{B0,B1,A0} -> X1 (6 loads)
  STG_A(X0, 0, 0); STG_A(X0, 0, 1);
  STG_B(X0, 0, 0); STG_B(X0, 0, 1);
  STG_B(X1, 1, 0); STG_B(X1, 1, 1);
  STG_A(X1, 1, 0);
  VM6();           // T0's 8 landed; T1's 6 in flight
  BAR();

  for (int it = 0; it < NKT / 2; ++it) {
    const int t0 = 2 * it;
    BLOCK4(X0, X1, (t0 + 1) & 15, (t0 + 2) & 15);
    BLOCK4(X1, X0, (t0 + 2) & 15, (t0 + 3) & 15);
  }

  // ---- fused LSTM epilogue ----
  // C/D layout: col = lane&15, row = (lane>>4)*4 + j.
  const size_t outC = (size_t)MDIM * NDIM;
  const int cc = bcol + wc * 16 + r15;
  const float bi = b_i[cc], bff = b_f[cc], bg = b_g[cc], bo = b_o[cc];
#pragma unroll
  for (int m = 0; m < 8; ++m) {
#pragma unroll
    for (int j = 0; j < 4; ++j) {
      int rr = brow + wr * 128 + m * 16 + hh * 4 + j;
      size_t base = (size_t)rr * NDIM + cc;
      float pi = acc[0][m][j] + bi;
      float pf = acc[1][m][j] + bff;
      float pg = acc[2][m][j] + bg;
      float po = acc[3][m][j] + bo;
      float iv = fast_sigmoid(pi);
      float fv = fast_sigmoid(pf);
      float gv = fast_tanh(pg);
      float ov = fast_sigmoid(po);
      float cp = fv * cprev[base] + iv * gv;
      float hp = ov * fast_tanh(cp);
      out[base] = hp;
      out[outC + base] = cp;
    }
  }
}

// ---------- launch ----------

extern "C" void kernel_launch(void* const* d_in, const int* in_sizes, int n_in,
                              void* d_out, int out_size, void* d_ws, size_t ws_size,
                              hipStream_t stream) {
  const float* hprev = (const float*)d_in[0];
  const float* cprev = (const float*)d_in[1];
  const float* w_hi  = (const float*)d_in[2];
  const float* b_hi  = (const float*)d_in[3];
  const float* w_hf  = (const float*)d_in[4];
  const float* b_hf  = (const float*)d_in[5];
  const float* w_hg  = (const float*)d_in[6];
  const float* b_hg  = (const float*)d_in[7];
  const float* w_ho  = (const float*)d_in[8];
  const float* b_ho  = (const float*)d_in[9];
  float* out = (float*)d_out;

  // ws: [0,16MB) A_t; [16MB,24MB) B_t
  unsigned short* At = (unsigned short*)d_ws;
  unsigned short* Bt = (unsigned short*)((char*)d_ws + (size_t)NKT * MDIM * 64 * 2);

  convert_h_tiled<<<2048, 256, 0, stream>>>(hprev, At, MDIM * KDIM / 8);
  convert_w_tiled<<<dim3(16, 16, 4), dim3(64, 4, 1), 0, stream>>>(
      w_hi, w_hf, w_hg, w_ho, Bt);
  lstm_fused_gemm<<<512, 512, 131072, stream>>>(At, Bt, cprev,
                                                b_hi, b_hf, b_hg, b_ho, out);
}